// Round 11
// baseline (469.090 us; speedup 1.0000x reference)
//
#include <hip/hip_runtime.h>

#define N_NODES 16384
#define N_EDGES 524288
#define TILE_I 16      // rows per block
#define TILE_J 2048    // 8 waves x 256 j
// grid = (16384/16) * (16384/2048) = 1024 * 8 = 8192 blocks

typedef float f32x4 __attribute__((ext_vector_type(4)));

// ---------------- kernel 1: scatter-add neighbor features ----------------
__global__ void scatter_kernel(const int* __restrict__ eidx,
                               const float* __restrict__ x,
                               float* __restrict__ agg) {
    int e = blockIdx.x * blockDim.x + threadIdx.x;
    if (e >= N_EDGES) return;
    int s = eidx[e];            // src row
    int t = eidx[N_EDGES + e];  // tgt row
    float f0 = x[s * 3 + 0];
    float f1 = x[s * 3 + 1];
    float f2 = x[s * 3 + 2];
    atomicAdd(&agg[t * 3 + 0], f0);
    atomicAdd(&agg[t * 3 + 1], f1);
    atomicAdd(&agg[t * 3 + 2], f2);
}

// ---------------- kernel 2: GIN MLP per node -> h [N,16] ----------------
__global__ void mlp_kernel(const float* __restrict__ x,
                           const float* __restrict__ agg,
                           const float* __restrict__ W1,
                           const float* __restrict__ b1,
                           const float* __restrict__ W2,
                           const float* __restrict__ b2,
                           const float* __restrict__ eps_p,
                           float* __restrict__ h) {
    int n = blockIdx.x * blockDim.x + threadIdx.x;
    if (n >= N_NODES) return;
    float se = 1.0f + eps_p[0];
    float z0 = se * x[n * 3 + 0] + agg[n * 3 + 0];
    float z1 = se * x[n * 3 + 1] + agg[n * 3 + 1];
    float z2 = se * x[n * 3 + 2] + agg[n * 3 + 2];
    float h1[16];
#pragma unroll
    for (int j = 0; j < 16; ++j) {
        float a = b1[j];
        a += z0 * W1[0 * 16 + j];
        a += z1 * W1[1 * 16 + j];
        a += z2 * W1[2 * 16 + j];
        h1[j] = fmaxf(a, 0.0f);
    }
    float4* h4 = (float4*)&h[n * 16];
#pragma unroll
    for (int oq = 0; oq < 4; ++oq) {
        float4 o;
        float* op = (float*)&o;
#pragma unroll
        for (int c = 0; c < 4; ++c) {
            int oo = oq * 4 + c;
            float a = b2[oo];
#pragma unroll
            for (int j = 0; j < 16; ++j) a += h1[j] * W2[j * 16 + oo];
            op[c] = fmaxf(a, 0.0f);
        }
        h4[oq] = o;
    }
}

// ---------------- kernel 3: out[i][j] = dot(h[i], h[j]) ----------------
// R7 kernel, UNCHANGED (best: 269 us total). This round launches it TWICE
// to decompose total = prologue + 2*pairwise from dur_us alone -- the
// pairwise dispatch never appears in the rocprof top-5 (burried by 650 us
// harness fills), so its true duration has never been observed.
__global__ __launch_bounds__(512) void pairwise_kernel(const float* __restrict__ h,
                                                       float* __restrict__ out) {
    __shared__ float hi[TILE_I * 16];   // 1 KB
    const int i0 = (blockIdx.x >> 3) * TILE_I;
    const int j0 = (blockIdx.x & 7) * TILE_J;
    const int tid = threadIdx.x;
    const int wid = tid >> 6;
    const int lane = tid & 63;

    // stage hi panel: 16 rows x 4 f32x4 = 64 f32x4
    if (tid < TILE_I * 4) {
        ((f32x4*)hi)[tid] = ((const f32x4*)h)[(size_t)i0 * 4 + tid];
    }

    // load hj: this thread's 4 j-rows straight from global (h is L2-resident),
    // transposed to k-major f32x4 in registers.
    const int jbase = j0 + wid * 256 + lane * 4;
    const f32x4* hg = (const f32x4*)h;
    f32x4 hj[16];
#pragma unroll
    for (int jj = 0; jj < 4; ++jj) {
        const size_t jb4 = (size_t)(jbase + jj) * 4;
        f32x4 q0 = hg[jb4 + 0];
        f32x4 q1 = hg[jb4 + 1];
        f32x4 q2 = hg[jb4 + 2];
        f32x4 q3 = hg[jb4 + 3];
        hj[0][jj]  = q0.x;  hj[1][jj]  = q0.y;  hj[2][jj]  = q0.z;  hj[3][jj]  = q0.w;
        hj[4][jj]  = q1.x;  hj[5][jj]  = q1.y;  hj[6][jj]  = q1.z;  hj[7][jj]  = q1.w;
        hj[8][jj]  = q2.x;  hj[9][jj]  = q2.y;  hj[10][jj] = q2.z;  hj[11][jj] = q2.w;
        hj[12][jj] = q3.x;  hj[13][jj] = q3.y;  hj[14][jj] = q3.z;  hj[15][jj] = q3.w;
    }
    __syncthreads();

    f32x4* out4 = (f32x4*)out;
    const size_t obase = (size_t)i0 * (N_NODES / 4) + (size_t)(jbase >> 2);

#pragma unroll
    for (int r = 0; r < TILE_I; ++r) {
        const f32x4* hr = (const f32x4*)&hi[r * 16];
        f32x4 a0 = hr[0], a1 = hr[1], a2 = hr[2], a3 = hr[3];
        f32x4 acc = a0.x * hj[0];
        acc += a0.y * hj[1];
        acc += a0.z * hj[2];
        acc += a0.w * hj[3];
        acc += a1.x * hj[4];
        acc += a1.y * hj[5];
        acc += a1.z * hj[6];
        acc += a1.w * hj[7];
        acc += a2.x * hj[8];
        acc += a2.y * hj[9];
        acc += a2.z * hj[10];
        acc += a2.w * hj[11];
        acc += a3.x * hj[12];
        acc += a3.y * hj[13];
        acc += a3.z * hj[14];
        acc += a3.w * hj[15];
        __builtin_nontemporal_store(acc, &out4[obase + (size_t)r * (N_NODES / 4)]);
    }
}

extern "C" void kernel_launch(void* const* d_in, const int* in_sizes, int n_in,
                              void* d_out, int out_size, void* d_ws, size_t ws_size,
                              hipStream_t stream) {
    const float* node_feats = (const float*)d_in[0];
    const int*   edge_idx   = (const int*)d_in[1];
    const float* W1         = (const float*)d_in[2];
    const float* b1         = (const float*)d_in[3];
    const float* W2         = (const float*)d_in[4];
    const float* b2         = (const float*)d_in[5];
    const float* eps        = (const float*)d_in[6];
    float* out = (float*)d_out;

    // workspace layout: agg [N*3 floats] at 0, h [N*16 floats] at 256 KB
    float* agg = (float*)d_ws;
    float* h   = (float*)((char*)d_ws + 262144);

    hipMemsetAsync(agg, 0, N_NODES * 3 * sizeof(float), stream);
    scatter_kernel<<<N_EDGES / 256, 256, 0, stream>>>(edge_idx, node_feats, agg);
    mlp_kernel<<<N_NODES / 256, 256, 0, stream>>>(node_feats, agg, W1, b1, W2, b2, eps, h);

    // ATTRIBUTION PROBE: launch pairwise twice (idempotent rewrite of d_out).
    // total = prologue + 2*pairwise  ->  pairwise = total - 269.
    pairwise_kernel<<<8192, 512, 0, stream>>>(h, out);
    pairwise_kernel<<<8192, 512, 0, stream>>>(h, out);
}

// Round 12
// 310.052 us; speedup vs baseline: 1.5129x; 1.5129x over previous
//
#include <hip/hip_runtime.h>

#define N_NODES 16384
#define N_EDGES 524288
#define TILE_I 32      // rows per block
#define TILE_J 2048    // 8 waves x 256 j
#define N3 (N_NODES * 3)
// pairwise grid = (16384/32) * (16384/2048) = 512 * 8 = 4096 blocks

typedef float f32x4 __attribute__((ext_vector_type(4)));

// ---------------- kernel 1: scatter-add neighbor features ----------------
// nc-way split accumulation: block b atomics into copy (b & (nc-1)).
// Disjoint copies cut cross-XCD coherence contention on hot lines.
__global__ void scatter_kernel(const int* __restrict__ eidx,
                               const float* __restrict__ x,
                               float* __restrict__ splits,
                               int nc_mask) {
    int e = blockIdx.x * blockDim.x + threadIdx.x;
    if (e >= N_EDGES) return;
    float* agg = splits + (size_t)(blockIdx.x & nc_mask) * N3;
    int s = eidx[e];            // src row
    int t = eidx[N_EDGES + e];  // tgt row
    float f0 = x[s * 3 + 0];
    float f1 = x[s * 3 + 1];
    float f2 = x[s * 3 + 2];
    atomicAdd(&agg[t * 3 + 0], f0);
    atomicAdd(&agg[t * 3 + 1], f1);
    atomicAdd(&agg[t * 3 + 2], f2);
}

// ---------------- kernel 2: GIN MLP per node -> h [N,16] ----------------
__global__ void mlp_kernel(const float* __restrict__ x,
                           const float* __restrict__ splits,
                           int nc,
                           const float* __restrict__ W1,
                           const float* __restrict__ b1,
                           const float* __restrict__ W2,
                           const float* __restrict__ b2,
                           const float* __restrict__ eps_p,
                           float* __restrict__ h) {
    int n = blockIdx.x * blockDim.x + threadIdx.x;
    if (n >= N_NODES) return;
    float a0 = 0.f, a1 = 0.f, a2 = 0.f;
    for (int k = 0; k < nc; ++k) {
        const float* ag = splits + (size_t)k * N3;
        a0 += ag[n * 3 + 0];
        a1 += ag[n * 3 + 1];
        a2 += ag[n * 3 + 2];
    }
    float se = 1.0f + eps_p[0];
    float z0 = se * x[n * 3 + 0] + a0;
    float z1 = se * x[n * 3 + 1] + a1;
    float z2 = se * x[n * 3 + 2] + a2;
    float h1[16];
#pragma unroll
    for (int j = 0; j < 16; ++j) {
        float a = b1[j];
        a += z0 * W1[0 * 16 + j];
        a += z1 * W1[1 * 16 + j];
        a += z2 * W1[2 * 16 + j];
        h1[j] = fmaxf(a, 0.0f);
    }
    float4* h4 = (float4*)&h[n * 16];
#pragma unroll
    for (int oq = 0; oq < 4; ++oq) {
        float4 o;
        float* op = (float*)&o;
#pragma unroll
        for (int c = 0; c < 4; ++c) {
            int oo = oq * 4 + c;
            float a = b2[oo];
#pragma unroll
            for (int j = 0; j < 16; ++j) a += h1[j] * W2[j * 16 + oo];
            op[c] = fmaxf(a, 0.0f);
        }
        h4[oq] = o;
    }
}

// ---------------- kernel 3: out[i][j] = dot(h[i], h[j]) ----------------
// R7 structure, TILE_I 16 -> 32: halves hj L2 re-read traffic (1 GB -> 0.5
// GB) and block generations (8192 -> 4096). Per r the 8 waves still write
// 8 KB contiguous (NT). Measured R11: this kernel runs at 5.4 TB/s write.
__global__ __launch_bounds__(512) void pairwise_kernel(const float* __restrict__ h,
                                                       float* __restrict__ out) {
    __shared__ float hi[TILE_I * 16];   // 2 KB
    const int i0 = (blockIdx.x >> 3) * TILE_I;
    const int j0 = (blockIdx.x & 7) * TILE_J;
    const int tid = threadIdx.x;
    const int wid = tid >> 6;
    const int lane = tid & 63;

    // stage hi panel: 32 rows x 4 f32x4 = 128 f32x4
    if (tid < TILE_I * 4) {
        ((f32x4*)hi)[tid] = ((const f32x4*)h)[(size_t)i0 * 4 + tid];
    }

    // load hj: this thread's 4 j-rows straight from global (h is L2-resident),
    // transposed to k-major f32x4 in registers (static indices only).
    const int jbase = j0 + wid * 256 + lane * 4;
    const f32x4* hg = (const f32x4*)h;
    f32x4 hj[16];
#pragma unroll
    for (int jj = 0; jj < 4; ++jj) {
        const size_t jb4 = (size_t)(jbase + jj) * 4;
        f32x4 q0 = hg[jb4 + 0];
        f32x4 q1 = hg[jb4 + 1];
        f32x4 q2 = hg[jb4 + 2];
        f32x4 q3 = hg[jb4 + 3];
        hj[0][jj]  = q0.x;  hj[1][jj]  = q0.y;  hj[2][jj]  = q0.z;  hj[3][jj]  = q0.w;
        hj[4][jj]  = q1.x;  hj[5][jj]  = q1.y;  hj[6][jj]  = q1.z;  hj[7][jj]  = q1.w;
        hj[8][jj]  = q2.x;  hj[9][jj]  = q2.y;  hj[10][jj] = q2.z;  hj[11][jj] = q2.w;
        hj[12][jj] = q3.x;  hj[13][jj] = q3.y;  hj[14][jj] = q3.z;  hj[15][jj] = q3.w;
    }
    __syncthreads();

    f32x4* out4 = (f32x4*)out;
    const size_t obase = (size_t)i0 * (N_NODES / 4) + (size_t)(jbase >> 2);

#pragma unroll
    for (int r = 0; r < TILE_I; ++r) {
        const f32x4* hr = (const f32x4*)&hi[r * 16];
        f32x4 a0 = hr[0], a1 = hr[1], a2 = hr[2], a3 = hr[3];
        f32x4 acc = a0.x * hj[0];
        acc += a0.y * hj[1];
        acc += a0.z * hj[2];
        acc += a0.w * hj[3];
        acc += a1.x * hj[4];
        acc += a1.y * hj[5];
        acc += a1.z * hj[6];
        acc += a1.w * hj[7];
        acc += a2.x * hj[8];
        acc += a2.y * hj[9];
        acc += a2.z * hj[10];
        acc += a2.w * hj[11];
        acc += a3.x * hj[12];
        acc += a3.y * hj[13];
        acc += a3.z * hj[14];
        acc += a3.w * hj[15];
        __builtin_nontemporal_store(acc, &out4[obase + (size_t)r * (N_NODES / 4)]);
    }
}

extern "C" void kernel_launch(void* const* d_in, const int* in_sizes, int n_in,
                              void* d_out, int out_size, void* d_ws, size_t ws_size,
                              hipStream_t stream) {
    const float* node_feats = (const float*)d_in[0];
    const int*   edge_idx   = (const int*)d_in[1];
    const float* W1         = (const float*)d_in[2];
    const float* b1         = (const float*)d_in[3];
    const float* W2         = (const float*)d_in[4];
    const float* b2         = (const float*)d_in[5];
    const float* eps        = (const float*)d_in[6];
    float* out = (float*)d_out;

    // workspace layout: h [N*16 floats, 1 MB] at 0; split agg buffers after.
    float* h      = (float*)d_ws;
    float* splits = (float*)((char*)d_ws + (size_t)N_NODES * 16 * sizeof(float));

    // 8-way split if workspace allows (8 x 192 KB + 1 MB), else single.
    const size_t need8 = (size_t)N_NODES * 16 * 4 + 8 * (size_t)N3 * 4;
    const int nc = (ws_size >= need8) ? 8 : 1;

    hipMemsetAsync(splits, 0, (size_t)nc * N3 * sizeof(float), stream);
    scatter_kernel<<<N_EDGES / 256, 256, 0, stream>>>(edge_idx, node_feats, splits, nc - 1);
    mlp_kernel<<<N_NODES / 256, 256, 0, stream>>>(node_feats, splits, nc, W1, b1, W2, b2, eps, h);

    pairwise_kernel<<<4096, 512, 0, stream>>>(h, out);
}

// Round 13
// 309.684 us; speedup vs baseline: 1.5147x; 1.0012x over previous
//
#include <hip/hip_runtime.h>

#define N_NODES 16384
#define N_EDGES 524288
#define TILE_I 32      // rows per block (A/B vs R7's 16; only change vs R7)
#define TILE_J 2048    // 8 waves x 256 j
// pairwise grid = (16384/32) * (16384/2048) = 512 * 8 = 4096 blocks

typedef float f32x4 __attribute__((ext_vector_type(4)));

// ---------------- kernel 1: scatter-add neighbor features ----------------
// R7 version: single agg buffer (R12's 8-way split is one of two suspects
// for the +41 us regression; removed for single-variable attribution).
__global__ void scatter_kernel(const int* __restrict__ eidx,
                               const float* __restrict__ x,
                               float* __restrict__ agg) {
    int e = blockIdx.x * blockDim.x + threadIdx.x;
    if (e >= N_EDGES) return;
    int s = eidx[e];            // src row
    int t = eidx[N_EDGES + e];  // tgt row
    float f0 = x[s * 3 + 0];
    float f1 = x[s * 3 + 1];
    float f2 = x[s * 3 + 2];
    atomicAdd(&agg[t * 3 + 0], f0);
    atomicAdd(&agg[t * 3 + 1], f1);
    atomicAdd(&agg[t * 3 + 2], f2);
}

// ---------------- kernel 2: GIN MLP per node -> h [N,16] ----------------
__global__ void mlp_kernel(const float* __restrict__ x,
                           const float* __restrict__ agg,
                           const float* __restrict__ W1,
                           const float* __restrict__ b1,
                           const float* __restrict__ W2,
                           const float* __restrict__ b2,
                           const float* __restrict__ eps_p,
                           float* __restrict__ h) {
    int n = blockIdx.x * blockDim.x + threadIdx.x;
    if (n >= N_NODES) return;
    float se = 1.0f + eps_p[0];
    float z0 = se * x[n * 3 + 0] + agg[n * 3 + 0];
    float z1 = se * x[n * 3 + 1] + agg[n * 3 + 1];
    float z2 = se * x[n * 3 + 2] + agg[n * 3 + 2];
    float h1[16];
#pragma unroll
    for (int j = 0; j < 16; ++j) {
        float a = b1[j];
        a += z0 * W1[0 * 16 + j];
        a += z1 * W1[1 * 16 + j];
        a += z2 * W1[2 * 16 + j];
        h1[j] = fmaxf(a, 0.0f);
    }
    float4* h4 = (float4*)&h[n * 16];
#pragma unroll
    for (int oq = 0; oq < 4; ++oq) {
        float4 o;
        float* op = (float*)&o;
#pragma unroll
        for (int c = 0; c < 4; ++c) {
            int oo = oq * 4 + c;
            float a = b2[oo];
#pragma unroll
            for (int j = 0; j < 16; ++j) a += h1[j] * W2[j * 16 + oo];
            op[c] = fmaxf(a, 0.0f);
        }
        h4[oq] = o;
    }
}

// ---------------- kernel 3: out[i][j] = dot(h[i], h[j]) ----------------
// R12's TILE_I=32 variant (the other regression suspect). vs R7: halves hj
// L2 re-read traffic (1 GB -> 0.5 GB) and block count (8192 -> 4096).
// Measured R11 baseline at TILE_I=16: 200 us (5.4 TB/s write).
__global__ __launch_bounds__(512) void pairwise_kernel(const float* __restrict__ h,
                                                       float* __restrict__ out) {
    __shared__ float hi[TILE_I * 16];   // 2 KB
    const int i0 = (blockIdx.x >> 3) * TILE_I;
    const int j0 = (blockIdx.x & 7) * TILE_J;
    const int tid = threadIdx.x;
    const int wid = tid >> 6;
    const int lane = tid & 63;

    // stage hi panel: 32 rows x 4 f32x4 = 128 f32x4
    if (tid < TILE_I * 4) {
        ((f32x4*)hi)[tid] = ((const f32x4*)h)[(size_t)i0 * 4 + tid];
    }

    // load hj: this thread's 4 j-rows straight from global (h is L2-resident),
    // transposed to k-major f32x4 in registers (static indices only).
    const int jbase = j0 + wid * 256 + lane * 4;
    const f32x4* hg = (const f32x4*)h;
    f32x4 hj[16];
#pragma unroll
    for (int jj = 0; jj < 4; ++jj) {
        const size_t jb4 = (size_t)(jbase + jj) * 4;
        f32x4 q0 = hg[jb4 + 0];
        f32x4 q1 = hg[jb4 + 1];
        f32x4 q2 = hg[jb4 + 2];
        f32x4 q3 = hg[jb4 + 3];
        hj[0][jj]  = q0.x;  hj[1][jj]  = q0.y;  hj[2][jj]  = q0.z;  hj[3][jj]  = q0.w;
        hj[4][jj]  = q1.x;  hj[5][jj]  = q1.y;  hj[6][jj]  = q1.z;  hj[7][jj]  = q1.w;
        hj[8][jj]  = q2.x;  hj[9][jj]  = q2.y;  hj[10][jj] = q2.z;  hj[11][jj] = q2.w;
        hj[12][jj] = q3.x;  hj[13][jj] = q3.y;  hj[14][jj] = q3.z;  hj[15][jj] = q3.w;
    }
    __syncthreads();

    f32x4* out4 = (f32x4*)out;
    const size_t obase = (size_t)i0 * (N_NODES / 4) + (size_t)(jbase >> 2);

#pragma unroll
    for (int r = 0; r < TILE_I; ++r) {
        const f32x4* hr = (const f32x4*)&hi[r * 16];
        f32x4 a0 = hr[0], a1 = hr[1], a2 = hr[2], a3 = hr[3];
        f32x4 acc = a0.x * hj[0];
        acc += a0.y * hj[1];
        acc += a0.z * hj[2];
        acc += a0.w * hj[3];
        acc += a1.x * hj[4];
        acc += a1.y * hj[5];
        acc += a1.z * hj[6];
        acc += a1.w * hj[7];
        acc += a2.x * hj[8];
        acc += a2.y * hj[9];
        acc += a2.z * hj[10];
        acc += a2.w * hj[11];
        acc += a3.x * hj[12];
        acc += a3.y * hj[13];
        acc += a3.z * hj[14];
        acc += a3.w * hj[15];
        __builtin_nontemporal_store(acc, &out4[obase + (size_t)r * (N_NODES / 4)]);
    }
}

extern "C" void kernel_launch(void* const* d_in, const int* in_sizes, int n_in,
                              void* d_out, int out_size, void* d_ws, size_t ws_size,
                              hipStream_t stream) {
    const float* node_feats = (const float*)d_in[0];
    const int*   edge_idx   = (const int*)d_in[1];
    const float* W1         = (const float*)d_in[2];
    const float* b1         = (const float*)d_in[3];
    const float* W2         = (const float*)d_in[4];
    const float* b2         = (const float*)d_in[5];
    const float* eps        = (const float*)d_in[6];
    float* out = (float*)d_out;

    // workspace layout (R7): agg [N*3 floats] at 0, h [N*16 floats] at 256 KB
    float* agg = (float*)d_ws;
    float* h   = (float*)((char*)d_ws + 262144);

    hipMemsetAsync(agg, 0, N_NODES * 3 * sizeof(float), stream);
    scatter_kernel<<<N_EDGES / 256, 256, 0, stream>>>(edge_idx, node_feats, agg);
    mlp_kernel<<<N_NODES / 256, 256, 0, stream>>>(node_feats, agg, W1, b1, W2, b2, eps, h);

    pairwise_kernel<<<4096, 512, 0, stream>>>(h, out);
}